// Round 1
// 277.767 us; speedup vs baseline: 1.0626x; 1.0626x over previous
//
#include <hip/hip_runtime.h>
#include <math.h>

#define NN 50000
#define EE 800000
#define ET (EE + NN)      // edges + self loops
#define F_IN 128
#define HEADS 8
#define HID 16
#define C1 (HEADS * HID)  // 128
#define CLASSES 40
#define NEG_SLOPE 0.2f
#define LOG2E 1.4426950408889634f

#define GB1 ((NN + 31) / 32)        // 1563 gemm1 blocks
#define CB1 ((EE / 4 + 255) / 256)  // 782 count blocks
#define NCHUNKS ((NN + 1023) / 1024)  // 49

typedef __attribute__((ext_vector_type(8))) short bf16x8;
typedef __attribute__((ext_vector_type(4))) float f32x4;
typedef __attribute__((ext_vector_type(2))) float f32x2;

__device__ __forceinline__ unsigned cvtpk(float a, float b) {
    unsigned r;
    asm("v_cvt_pk_bf16_f32 %0, %1, %2" : "=v"(r) : "v"(a), "v"(b));
    return r;
}
__device__ __forceinline__ float fexp2(float x) {
    float r;
    asm("v_exp_f32 %0, %1\n\ts_nop 0" : "=v"(r) : "v"(x));
    return r;
}
__device__ __forceinline__ f32x2 pkfma(f32x2 a, f32x2 b, f32x2 c) {
    f32x2 d;
    asm("v_pk_fma_f32 %0, %1, %2, %3" : "=v"(d) : "v"(a), "v"(b), "v"(c));
    return d;
}
__device__ __forceinline__ float bflo(unsigned u) { return __uint_as_float(u << 16); }
__device__ __forceinline__ float bfhi(unsigned u) { return __uint_as_float(u & 0xffff0000u); }
__device__ __forceinline__ f32x2 unp(unsigned u) {
    f32x2 t;
    t.x = bflo(u);
    t.y = bfhi(u);
    return t;
}
__device__ __forceinline__ float lrelu(float a) { return fmaxf(a, NEG_SLOPE * a); }
__device__ __forceinline__ bf16x8 pack8(float f0, float f1, float f2, float f3,
                                        float f4, float f5, float f6, float f7) {
    union { unsigned u[4]; bf16x8 v; } U;
    U.u[0] = cvtpk(f0, f1);
    U.u[1] = cvtpk(f2, f3);
    U.u[2] = cvtpk(f4, f5);
    U.u[3] = cvtpk(f6, f7);
    return U.v;
}

// ---------------- GEMM1 + elogit1 epilogue, with count fused by block range ----------------
__global__ void gemm1_count_kernel(const float* __restrict__ x, const float* __restrict__ W1,
                                   const float* __restrict__ a_src, const float* __restrict__ a_dst,
                                   const int* __restrict__ ei,
                                   unsigned short* __restrict__ h1b,
                                   float* __restrict__ e_src, float* __restrict__ e_dst,
                                   int* __restrict__ deg) {
    const int bid = blockIdx.x;
    const int tid = threadIdx.x;
    if (bid >= GB1) {  // -------- count part (independent of gemm; overlaps it) --------
        int base = ((bid - GB1) * 256 + tid) * 4;
        if (base < EE) {
            int4 d4 = *(const int4*)(ei + EE + base);
            atomicAdd(&deg[d4.x], 1);
            atomicAdd(&deg[d4.y], 1);
            atomicAdd(&deg[d4.z], 1);
            atomicAdd(&deg[d4.w], 1);
        }
        return;
    }
    const int w = tid >> 6, lane = tid & 63;
    const int q = lane >> 4, c = lane & 15;

    bf16x8 bfrag[2][4];
    #pragma unroll
    for (int nt = 0; nt < 2; ++nt) {
        const int col = w * 32 + nt * 16 + c;
        #pragma unroll
        for (int kc = 0; kc < 4; ++kc) {
            const int k0 = kc * 32 + q * 8;
            const float* wp = W1 + (size_t)k0 * C1 + col;
            bfrag[nt][kc] = pack8(wp[0], wp[C1], wp[2 * C1], wp[3 * C1],
                                  wp[4 * C1], wp[5 * C1], wp[6 * C1], wp[7 * C1]);
        }
    }

    const float as0 = a_src[w * 32 + c];
    const float ad0 = a_dst[w * 32 + c];
    const float as1 = a_src[w * 32 + 16 + c];
    const float ad1 = a_dst[w * 32 + 16 + c];

    #pragma unroll
    for (int mt = 0; mt < 2; ++mt) {
        const int m0 = (bid * 2 + mt) * 16;
        if (m0 >= NN) break;
        int row = m0 + c;
        if (row > NN - 1) row = NN - 1;
        bf16x8 afrag[4];
        #pragma unroll
        for (int kc = 0; kc < 4; ++kc) {
            const float* xp = x + (size_t)row * F_IN + kc * 32 + q * 8;
            float4 p0 = *(const float4*)xp;
            float4 p1 = *(const float4*)(xp + 4);
            afrag[kc] = pack8(p0.x, p0.y, p0.z, p0.w, p1.x, p1.y, p1.z, p1.w);
        }
        f32x4 acc0 = {0.f, 0.f, 0.f, 0.f};
        f32x4 acc1 = {0.f, 0.f, 0.f, 0.f};
        #pragma unroll
        for (int kc = 0; kc < 4; ++kc) {
            acc0 = __builtin_amdgcn_mfma_f32_16x16x32_bf16(afrag[kc], bfrag[0][kc], acc0, 0, 0, 0);
            acc1 = __builtin_amdgcn_mfma_f32_16x16x32_bf16(afrag[kc], bfrag[1][kc], acc1, 0, 0, 0);
        }
        #pragma unroll
        for (int r = 0; r < 4; ++r) {
            const int ro = m0 + q * 4 + r;
            if (ro < NN) {
                h1b[(size_t)ro * C1 + w * 32 + c]      = (unsigned short)cvtpk(acc0[r], acc0[r]);
                h1b[(size_t)ro * C1 + w * 32 + 16 + c] = (unsigned short)cvtpk(acc1[r], acc1[r]);
            }
            // fused elogit1: per-head dot over the 16 c-lanes (f32 acc, closer to ref)
            float ps0 = acc0[r] * as0, pd0 = acc0[r] * ad0;
            float ps1 = acc1[r] * as1, pd1 = acc1[r] * ad1;
            #pragma unroll
            for (int m = 1; m < 16; m <<= 1) {
                ps0 += __shfl_xor(ps0, m);
                pd0 += __shfl_xor(pd0, m);
                ps1 += __shfl_xor(ps1, m);
                pd1 += __shfl_xor(pd1, m);
            }
            if (c == 0 && ro < NN) {
                // pre-scale by log2(e): agg uses exp2 directly
                float2 es = {ps0 * LOG2E, ps1 * LOG2E};
                float2 edv = {pd0 * LOG2E, pd1 * LOG2E};
                *(float2*)(e_src + (size_t)ro * HEADS + 2 * w) = es;
                *(float2*)(e_dst + (size_t)ro * HEADS + 2 * w) = edv;
            }
        }
    }
}

// ---------------- CSR scan ----------------
// exclusive scan over (deg[i] + 1)  [+1 = self-loop]
__global__ void scan1_kernel(const int* __restrict__ deg, int* __restrict__ rowptr,
                             int* __restrict__ bsum) {
    __shared__ int sh[256];
    const int tid = threadIdx.x;
    const int base = blockIdx.x * 1024 + tid * 4;
    int v[4], s[4];
    #pragma unroll
    for (int j = 0; j < 4; ++j) v[j] = (base + j < NN) ? (deg[base + j] + 1) : 0;
    s[0] = v[0]; s[1] = s[0] + v[1]; s[2] = s[1] + v[2]; s[3] = s[2] + v[3];
    int T = s[3];
    sh[tid] = T;
    __syncthreads();
    for (int off = 1; off < 256; off <<= 1) {
        int xv = (tid >= off) ? sh[tid - off] : 0;
        __syncthreads();
        sh[tid] += xv;
        __syncthreads();
    }
    int excl = sh[tid] - T;
    #pragma unroll
    for (int j = 0; j < 4; ++j)
        if (base + j < NN) rowptr[base + j] = excl + s[j] - v[j];
    if (tid == 255) bsum[blockIdx.x] = sh[255];
}

// finalize rowptr (scan2 fused: wave-0 shfl_up scan of the 49 block sums);
// self-loop at slot rowptr[i]; cursor starts past it; deg -> total cnt
__global__ void scan3_kernel(int* __restrict__ rowptr, const int* __restrict__ bsum,
                             int* __restrict__ cursor, unsigned short* __restrict__ csr,
                             int* __restrict__ deg) {
    __shared__ int ex[64];
    const int tid = threadIdx.x;
    if (tid < 64) {
        int v = (tid < NCHUNKS) ? bsum[tid] : 0;
        int s = v;
        #pragma unroll
        for (int off = 1; off < 64; off <<= 1) {
            int xv = __shfl_up(s, off);
            if (tid >= off) s += xv;
        }
        ex[tid] = s - v;  // exclusive prefix
    }
    __syncthreads();
    int i = blockIdx.x * blockDim.x + tid;
    if (i >= NN) return;
    int rp = rowptr[i] + ex[i >> 10];
    rowptr[i] = rp;
    cursor[i] = rp + 1;
    csr[rp] = (unsigned short)i;  // self-loop first
    deg[i] += 1;                  // total incoming count incl. self-loop
}

// scatter real edges: 4 per thread, int4 loads, ushort payloads (L2-merged stores)
__global__ void fill_kernel(const int* __restrict__ ei, int* __restrict__ cursor,
                            unsigned short* __restrict__ csr) {
    int base = (blockIdx.x * blockDim.x + threadIdx.x) * 4;
    if (base >= EE) return;
    int4 s4 = *(const int4*)(ei + base);
    int4 d4 = *(const int4*)(ei + EE + base);
    int p0 = atomicAdd(&cursor[d4.x], 1);
    int p1 = atomicAdd(&cursor[d4.y], 1);
    int p2 = atomicAdd(&cursor[d4.z], 1);
    int p3 = atomicAdd(&cursor[d4.w], 1);
    csr[p0] = (unsigned short)s4.x;
    csr[p1] = (unsigned short)s4.y;
    csr[p2] = (unsigned short)s4.z;
    csr[p3] = (unsigned short)s4.w;
}

// ---------------- layer-1 aggregation (bf16 hmid out) ----------------
// block = 256 = 4 waves; wave per dst node. Wave = 4 edge-groups x 16 lanes.
// Lane l (0..15) owns channels 8l..8l+7; head = l>>1. Group g: edges i = g, g+4, ...
__global__ void agg1_kernel(const unsigned short* __restrict__ h1b,
                            const float* __restrict__ e_src, const float* __restrict__ e_dst,
                            const int* __restrict__ rowptr, const int* __restrict__ deg,
                            const unsigned short* __restrict__ csr,
                            const float* __restrict__ b1, unsigned short* __restrict__ hmid) {
    const int d = blockIdx.x * 4 + (threadIdx.x >> 6);
    const int lane = threadIdx.x & 63;
    const int g = lane >> 4;       // edge-group 0..3
    const int l = lane & 15;       // channel-lane: channels 8l..8l+7
    const int hd = l >> 1;
    const float ed = e_dst[(size_t)d * HEADS + hd];  // pre-scaled by log2e
    const int start = rowptr[d];
    const int cnt = deg[d];

    float denom = 0.f;
    f32x2 accp[4] = {{0.f, 0.f}, {0.f, 0.f}, {0.f, 0.f}, {0.f, 0.f}};

    for (int i = g; i < cnt; i += 8) {
        const int i1 = i + 4;
        const bool v1 = i1 < cnt;
        const int j1 = v1 ? i1 : i;
        int s0 = csr[start + i];
        int s1 = csr[start + j1];
        float es0 = e_src[(size_t)s0 * HEADS + hd];
        float es1 = e_src[(size_t)s1 * HEADS + hd];
        uint4 g0 = *(const uint4*)(h1b + (size_t)s0 * C1 + 8 * l);
        uint4 g1 = *(const uint4*)(h1b + (size_t)s1 * C1 + 8 * l);
        float z0 = es0 + ed, z1 = es1 + ed;
        float w0 = fexp2(lrelu(z0));
        float w1 = v1 ? fexp2(lrelu(z1)) : 0.f;
        denom += w0 + w1;
        f32x2 w0p = {w0, w0}, w1p = {w1, w1};
        accp[0] = pkfma(unp(g0.x), w0p, accp[0]);
        accp[1] = pkfma(unp(g0.y), w0p, accp[1]);
        accp[2] = pkfma(unp(g0.z), w0p, accp[2]);
        accp[3] = pkfma(unp(g0.w), w0p, accp[3]);
        accp[0] = pkfma(unp(g1.x), w1p, accp[0]);
        accp[1] = pkfma(unp(g1.y), w1p, accp[1]);
        accp[2] = pkfma(unp(g1.z), w1p, accp[2]);
        accp[3] = pkfma(unp(g1.w), w1p, accp[3]);
    }
    // combine the 4 edge-groups (lanes l, l+16, l+32, l+48)
    denom += __shfl_xor(denom, 16);
    denom += __shfl_xor(denom, 32);
    float acc[8] = {accp[0].x, accp[0].y, accp[1].x, accp[1].y,
                    accp[2].x, accp[2].y, accp[3].x, accp[3].y};
    #pragma unroll
    for (int k = 0; k < 8; ++k) {
        acc[k] += __shfl_xor(acc[k], 16);
        acc[k] += __shfl_xor(acc[k], 32);
    }
    if (g == 0) {
        const float inv = 1.f / (denom + 1e-16f);
        float o[8];
        #pragma unroll
        for (int k = 0; k < 8; ++k) {
            float t = acc[k] * inv + b1[8 * l + k];
            o[k] = (t > 0.f) ? t : expm1f(t);
        }
        uint4 st;
        st.x = cvtpk(o[0], o[1]);
        st.y = cvtpk(o[2], o[3]);
        st.z = cvtpk(o[4], o[5]);
        st.w = cvtpk(o[6], o[7]);
        *(uint4*)(hmid + (size_t)d * C1 + 8 * l) = st;  // bf16 row, 16B/lane
    }
}

// ---------------- GEMM2 (bf16 A direct) + elogit2 epilogue ----------------
__global__ void gemm2_kernel(const unsigned short* __restrict__ hmid, const float* __restrict__ W2,
                             const float* __restrict__ a_src, const float* __restrict__ a_dst,
                             unsigned short* __restrict__ h2b,
                             float* __restrict__ e_src, float* __restrict__ e_dst) {
    const int tid = threadIdx.x;
    const int w = tid >> 6, lane = tid & 63;
    const int q = lane >> 4, c = lane & 15;

    bf16x8 bfrag[3][4];
    float as2[3], ad2[3];
    #pragma unroll
    for (int nt = 0; nt < 3; ++nt) {
        const int col = nt * 16 + c;
        const bool cv = col < CLASSES;
        as2[nt] = cv ? a_src[col] : 0.f;
        ad2[nt] = cv ? a_dst[col] : 0.f;
        #pragma unroll
        for (int kc = 0; kc < 4; ++kc) {
            const int k0 = kc * 32 + q * 8;
            bf16x8 bb = 0;
            if (cv) {
                const float* wp = W2 + (size_t)k0 * CLASSES + col;
                bb = pack8(wp[0], wp[CLASSES], wp[2 * CLASSES], wp[3 * CLASSES],
                           wp[4 * CLASSES], wp[5 * CLASSES], wp[6 * CLASSES], wp[7 * CLASSES]);
            }
            bfrag[nt][kc] = bb;
        }
    }

    const int m0 = (blockIdx.x * 4 + w) * 16;
    if (m0 >= NN) return;
    int row = m0 + c;
    if (row > NN - 1) row = NN - 1;
    bf16x8 afrag[4];
    #pragma unroll
    for (int kc = 0; kc < 4; ++kc)
        afrag[kc] = *(const bf16x8*)(hmid + (size_t)row * C1 + kc * 32 + q * 8);  // no converts

    f32x4 acc[3] = {{0.f,0.f,0.f,0.f},{0.f,0.f,0.f,0.f},{0.f,0.f,0.f,0.f}};
    #pragma unroll
    for (int kc = 0; kc < 4; ++kc) {
        acc[0] = __builtin_amdgcn_mfma_f32_16x16x32_bf16(afrag[kc], bfrag[0][kc], acc[0], 0, 0, 0);
        acc[1] = __builtin_amdgcn_mfma_f32_16x16x32_bf16(afrag[kc], bfrag[1][kc], acc[1], 0, 0, 0);
        acc[2] = __builtin_amdgcn_mfma_f32_16x16x32_bf16(afrag[kc], bfrag[2][kc], acc[2], 0, 0, 0);
    }
    #pragma unroll
    for (int r = 0; r < 4; ++r) {
        const int ro = m0 + q * 4 + r;
        if (ro < NN) {
            #pragma unroll
            for (int nt = 0; nt < 3; ++nt) {
                const int col = nt * 16 + c;
                if (col < CLASSES)
                    h2b[(size_t)ro * CLASSES + col] = (unsigned short)cvtpk(acc[nt][r], acc[nt][r]);
            }
        }
        // fused elogit2 (f32 acc, closer to ref)
        float ps = acc[0][r] * as2[0] + acc[1][r] * as2[1] + acc[2][r] * as2[2];
        float pd = acc[0][r] * ad2[0] + acc[1][r] * ad2[1] + acc[2][r] * ad2[2];
        #pragma unroll
        for (int m = 1; m < 16; m <<= 1) {
            ps += __shfl_xor(ps, m);
            pd += __shfl_xor(pd, m);
        }
        if (c == 0 && ro < NN) {
            e_src[ro] = ps * LOG2E;
            e_dst[ro] = pd * LOG2E;
        }
    }
}

// ---------------- layer-2 aggregation -> output ----------------
// block = 256 = 4 waves; wave per dst node. Wave = 3 edge-groups x 20 lanes (60 active).
__global__ void agg2_kernel(const unsigned short* __restrict__ h2b,
                            const float* __restrict__ e_src, const float* __restrict__ e_dst,
                            const int* __restrict__ rowptr, const int* __restrict__ deg,
                            const unsigned short* __restrict__ csr,
                            const float* __restrict__ b2, float* __restrict__ out) {
    const int d = blockIdx.x * 4 + (threadIdx.x >> 6);
    const int lane = threadIdx.x & 63;
    const int eg = lane / 20;      // 0..2 active, 3 = idle lanes 60..63
    const int c  = lane % 20;
    const bool act = lane < 60;
    const float ed = e_dst[d];     // pre-scaled by log2e
    const int start = rowptr[d];
    const int cnt = deg[d];

    float denom = 0.f, acc0 = 0.f, acc1 = 0.f;
    for (int i = act ? eg : cnt; i < cnt; i += 6) {
        const int i1 = i + 3;
        const bool v1 = i1 < cnt;
        const int j1 = v1 ? i1 : i;
        int s0 = csr[start + i];
        int s1 = csr[start + j1];
        float es0 = e_src[s0], es1 = e_src[s1];
        unsigned g0 = *(const unsigned*)(h2b + (size_t)s0 * CLASSES + 2 * c);
        unsigned g1 = *(const unsigned*)(h2b + (size_t)s1 * CLASSES + 2 * c);
        float w0 = fexp2(lrelu(es0 + ed));
        float w1 = v1 ? fexp2(lrelu(es1 + ed)) : 0.f;
        denom += w0 + w1;
        acc0 += w0 * bflo(g0) + w1 * bflo(g1);
        acc1 += w0 * bfhi(g0) + w1 * bfhi(g1);
    }
    // combine 3 edge-groups: lanes c, c+20, c+40
    float dA = __shfl(denom, c + 20), dB = __shfl(denom, c + 40);
    float aA = __shfl(acc0,  c + 20), aB = __shfl(acc0,  c + 40);
    float bA = __shfl(acc1,  c + 20), bB = __shfl(acc1,  c + 40);
    if (lane < 20) {
        denom += dA + dB;
        acc0  += aA + aB;
        acc1  += bA + bB;
        const float inv = 1.f / (denom + 1e-16f);
        float2 o;
        o.x = acc0 * inv + b2[2 * c];
        o.y = acc1 * inv + b2[2 * c + 1];
        *(float2*)(out + (size_t)d * CLASSES + 2 * c) = o;
    }
}

extern "C" void kernel_launch(void* const* d_in, const int* in_sizes, int n_in,
                              void* d_out, int out_size, void* d_ws, size_t ws_size,
                              hipStream_t stream) {
    const float* x      = (const float*)d_in[0];
    const int*   ei     = (const int*)d_in[1];
    const float* W1     = (const float*)d_in[2];
    const float* a_src1 = (const float*)d_in[3];
    const float* a_dst1 = (const float*)d_in[4];
    const float* b1     = (const float*)d_in[5];
    const float* W2     = (const float*)d_in[6];
    const float* a_src2 = (const float*)d_in[7];
    const float* a_dst2 = (const float*)d_in[8];
    const float* b2     = (const float*)d_in[9];
    float* out = (float*)d_out;

    char* ws = (char*)d_ws;
    size_t off = 0;
    auto alloc = [&](size_t bytes) { char* p = ws + off; off += (bytes + 255) & ~(size_t)255; return p; };
    unsigned short* h1b   = (unsigned short*)alloc((size_t)NN * C1 * 2);
    unsigned short* h2b   = (unsigned short*)alloc((size_t)NN * CLASSES * 2);
    unsigned short* hmidb = (unsigned short*)alloc((size_t)NN * C1 * 2);  // bf16 now
    float* e_src1 = (float*)alloc((size_t)NN * HEADS * 4);
    float* e_dst1 = (float*)alloc((size_t)NN * HEADS * 4);
    float* e_src2 = (float*)alloc((size_t)NN * 4);
    float* e_dst2 = (float*)alloc((size_t)NN * 4);
    int*   deg    = (int*)alloc((size_t)NN * 4);
    int*   rowptr = (int*)alloc((size_t)NN * 4);
    int*   cursor = (int*)alloc((size_t)NN * 4);
    unsigned short* csr = (unsigned short*)alloc((size_t)ET * 2);
    int*   bsum   = (int*)alloc(256 * 4);

    hipMemsetAsync(deg, 0, (size_t)NN * 4, stream);

    gemm1_count_kernel<<<GB1 + CB1, 256, 0, stream>>>(x, W1, a_src1, a_dst1, ei,
                                                      h1b, e_src1, e_dst1, deg);
    scan1_kernel<<<NCHUNKS, 256, 0, stream>>>(deg, rowptr, bsum);
    scan3_kernel<<<(NN + 255) / 256, 256, 0, stream>>>(rowptr, bsum, cursor, csr, deg);
    fill_kernel<<<(EE / 4 + 255) / 256, 256, 0, stream>>>(ei, cursor, csr);

    agg1_kernel<<<NN / 4, 256, 0, stream>>>(h1b, e_src1, e_dst1, rowptr, deg, csr, b1, hmidb);

    gemm2_kernel<<<(NN + 63) / 64, 256, 0, stream>>>(hmidb, W2, a_src2, a_dst2,
                                                     h2b, e_src2, e_dst2);
    agg2_kernel<<<NN / 4, 256, 0, stream>>>(h2b, e_src2, e_dst2, rowptr, deg, csr, b2, out);
}